// Round 3
// baseline (748.575 us; speedup 1.0000x reference)
//
#include <hip/hip_runtime.h>
#include <hip/hip_bf16.h>

#define NN 50000
#define NE 1600000
#define NR 16
#define TM 32                    // dst rows per block tile
#define NTILE 1563               // ceil(50000/32)
#define NDP 50016                // NTILE*TM — padded dst bins per rel
#define NBINS (NR * NDP)         // 800256 (= 3126 * 256 exactly)
#define NSCB 3126                // NBINS / 256

typedef __bf16 bf16x8 __attribute__((ext_vector_type(8)));
typedef unsigned short u16x8 __attribute__((ext_vector_type(8)));
typedef float f32x4 __attribute__((ext_vector_type(4)));

__device__ __forceinline__ unsigned short f2bf(float f) {
    union { float f; unsigned int u; } v; v.f = f;
    unsigned int u = v.u;
    u += 0x7FFFu + ((u >> 16) & 1u);   // round-to-nearest-even
    return (unsigned short)(u >> 16);
}
__device__ __forceinline__ float bflo(unsigned int u) {
    union { unsigned int u; float f; } v; v.u = u << 16; return v.f;
}
__device__ __forceinline__ float bfhi(unsigned int u) {
    union { unsigned int u; float f; } v; v.u = u & 0xFFFF0000u; return v.f;
}

// ---------------- prep ----------------------------------------------------

// h_bf[n][k] = bf16(emb[node_ids[n]][k])
__global__ __launch_bounds__(256) void prep_h(const int* __restrict__ node_ids,
                                              const float* __restrict__ emb,
                                              unsigned short* __restrict__ h_bf) {
    int gid = blockIdx.x * 256 + threadIdx.x;
    if (gid >= NN * 32) return;
    int row = gid >> 5;
    int c = (gid & 31) << 2;
    int nid = node_ids[row];
    if (nid < 0) nid = 0; if (nid >= NN) nid = NN - 1;
    float4 v = *(const float4*)(emb + (size_t)nid * 128 + c);
    ushort4 o;
    o.x = f2bf(v.x); o.y = f2bf(v.y); o.z = f2bf(v.z); o.w = f2bf(v.w);
    *(ushort4*)(h_bf + (size_t)row * 128 + c) = o;
}

// Wt[r][o][k] = bf16(W[r][k][o])  (N-major so B-fragments are k-contiguous)
__global__ __launch_bounds__(256) void prep_w(const float* __restrict__ W,
                                              unsigned short* __restrict__ Wt) {
    int gid = blockIdx.x * 256 + threadIdx.x;
    if (gid >= NR * 128 * 128) return;
    int r = gid >> 14;
    int idx = gid & 16383;
    int k = idx >> 7;
    int o = idx & 127;
    Wt[(size_t)r * 16384 + (size_t)o * 128 + k] = f2bf(W[gid]);
}

// ---------------- counting sort by (rel, dst) -----------------------------

__global__ __launch_bounds__(256) void hist_key(const int* __restrict__ dst,
                                                const int* __restrict__ rel,
                                                int* __restrict__ counts) {
    int e = blockIdx.x * 256 + threadIdx.x;
    if (e >= NE) return;
    atomicAdd(&counts[rel[e] * NDP + dst[e]], 1);
}

// per-256-block sums -> blockSums[NSCB]
__global__ __launch_bounds__(256) void scanA(const int* __restrict__ counts,
                                             int* __restrict__ blockSums) {
    __shared__ int s[256];
    int t = threadIdx.x;
    s[t] = counts[blockIdx.x * 256 + t];
    __syncthreads();
    for (int off = 128; off > 0; off >>= 1) {
        if (t < off) s[t] += s[t + off];
        __syncthreads();
    }
    if (t == 0) blockSums[blockIdx.x] = s[0];
}

// single-block exclusive scan of NSCB block sums (1024 thr x 4 elems)
__global__ __launch_bounds__(1024) void scanB(int* __restrict__ bs) {
    __shared__ int s[1024];
    int t = threadIdx.x;
    int v[4]; int tot = 0;
    #pragma unroll
    for (int k = 0; k < 4; ++k) {
        int idx = t * 4 + k;
        v[k] = (idx < NSCB) ? bs[idx] : 0;
        tot += v[k];
    }
    s[t] = tot;
    __syncthreads();
    for (int off = 1; off < 1024; off <<= 1) {
        int x = (t >= off) ? s[t - off] : 0;
        __syncthreads();
        s[t] += x;
        __syncthreads();
    }
    int run = s[t] - tot;          // exclusive base of this thread's chunk
    #pragma unroll
    for (int k = 0; k < 4; ++k) {
        int idx = t * 4 + k;
        if (idx < NSCB) bs[idx] = run;
        run += v[k];
    }
}

// per-block exclusive scan + base -> start2[], cursor (aliases counts)
__global__ __launch_bounds__(256) void scanC(int* __restrict__ counts,
                                             const int* __restrict__ bs,
                                             int* __restrict__ start2) {
    __shared__ int s[256];
    int t = threadIdx.x;
    int idx = blockIdx.x * 256 + t;
    int v = counts[idx];
    s[t] = v;
    __syncthreads();
    for (int off = 1; off < 256; off <<= 1) {
        int x = (t >= off) ? s[t - off] : 0;
        __syncthreads();
        s[t] += x;
        __syncthreads();
    }
    int excl = bs[blockIdx.x] + s[t] - v;
    start2[idx] = excl;
    counts[idx] = excl;            // becomes cursor for scatter_rank
    if (idx == 0) start2[NBINS] = NE;
}

// recs[pos] = {src, norm} in (rel,dst)-sorted order
__global__ __launch_bounds__(256) void scatter_rank(const int* __restrict__ src,
                                                    const int* __restrict__ dst,
                                                    const int* __restrict__ rel,
                                                    const float* __restrict__ norm,
                                                    int* __restrict__ cursor,
                                                    uint2* __restrict__ recs) {
    int e = blockIdx.x * 256 + threadIdx.x;
    if (e >= NE) return;
    int key = rel[e] * NDP + dst[e];
    int pos = atomicAdd(&cursor[key], 1);
    recs[pos] = make_uint2((unsigned int)src[e], __float_as_uint(norm[e]));
}

// ---------------- fused aggregate + transform -----------------------------
// Block = 32 dst rows x 128 out cols. For each rel r: build A-tile
// [32 x 128] = norm-weighted sum of gathered h_bf rows (per (d,r) run,
// register accumulate, one LDS write), then MFMA vs Wt[r] (global, L2-hot),
// accumulating C in registers across all 16 rels. No atomics, no h_rel.
__global__ __launch_bounds__(256, 6) void rgcn_fused(
        const int* __restrict__ start2,
        const uint2* __restrict__ recs,
        const unsigned int* __restrict__ hb,     // h_bf viewed as dwords [NN][64]
        const unsigned short* __restrict__ Wt,   // [NR][128 o][128 k]
        float* __restrict__ out) {
    __shared__ unsigned short sA[TM][136];       // +8 pad
    const int t = threadIdx.x;
    const int lane = t & 63;
    const int w = t >> 6;                        // 4 waves
    const int dtile = blockIdx.x * TM;
    const int l15 = lane & 15, lhi = lane >> 4;

    const int mrow = (w & 1) * 16;               // wave C tile: rows, cols
    const int ncol = (w >> 1) * 64;

    f32x4 acc[4];
    #pragma unroll
    for (int nt = 0; nt < 4; ++nt) acc[nt] = (f32x4){0.f, 0.f, 0.f, 0.f};

    for (int r = 0; r < NR; ++r) {
        // ---- build: wave w fills sA rows [w*8, w*8+8)
        int idx0 = r * NDP + dtile + w * 8;
        int b = (lane < 9) ? start2[idx0 + lane] : 0;
        for (int j = 0; j < 8; ++j) {
            int beg = __shfl(b, j), end = __shfl(b, j + 1);
            float a0 = 0.f, a1 = 0.f;
            for (int i = beg; i < end; ++i) {
                uint2 rc = recs[i];                       // broadcast 8B
                float nm = __uint_as_float(rc.y);
                unsigned int u = hb[(size_t)rc.x * 64 + lane];  // 256B row
                a0 += bflo(u) * nm;
                a1 += bfhi(u) * nm;
            }
            unsigned int pk = (unsigned int)f2bf(a0) |
                              ((unsigned int)f2bf(a1) << 16);
            *(unsigned int*)&sA[w * 8 + j][lane * 2] = pk;
        }
        __syncthreads();
        // ---- mfma: K=128 for this rel
        const unsigned short* wrp = Wt + ((size_t)r << 14);
        #pragma unroll
        for (int kt = 0; kt < 4; ++kt) {
            const int ko = kt * 32 + lhi * 8;
            u16x8 araw = *(const u16x8*)&sA[mrow + l15][ko];
            bf16x8 aF = __builtin_bit_cast(bf16x8, araw);
            #pragma unroll
            for (int nt = 0; nt < 4; ++nt) {
                u16x8 braw = *(const u16x8*)(wrp +
                        (size_t)(ncol + nt * 16 + l15) * 128 + ko);
                acc[nt] = __builtin_amdgcn_mfma_f32_16x16x32_bf16(
                        aF, __builtin_bit_cast(bf16x8, braw), acc[nt], 0, 0, 0);
            }
        }
        __syncthreads();
    }

    // ---- epilogue: D layout col=lane&15, row=(lane>>4)*4+reg
    #pragma unroll
    for (int reg = 0; reg < 4; ++reg) {
        int d = dtile + mrow + lhi * 4 + reg;
        if (d < NN) {
            #pragma unroll
            for (int nt = 0; nt < 4; ++nt)
                out[(size_t)d * 128 + ncol + nt * 16 + l15] = acc[nt][reg];
        }
    }
}

// ---------------- launch ---------------------------------------------------

extern "C" void kernel_launch(void* const* d_in, const int* in_sizes, int n_in,
                              void* d_out, int out_size, void* d_ws, size_t ws_size,
                              hipStream_t stream) {
    const int* node_ids = (const int*)d_in[0];
    const int* src      = (const int*)d_in[1];
    const int* dst      = (const int*)d_in[2];
    const int* rel      = (const int*)d_in[3];
    const float* norm   = (const float*)d_in[4];
    const float* emb    = (const float*)d_in[5];
    const float* W      = (const float*)d_in[6];
    float* out = (float*)d_out;

    char* ws = (char*)d_ws;
    unsigned short* h_bf = (unsigned short*)(ws);              // 12,800,000 B
    uint2* recs          = (uint2*)(ws + 12800000);            // 12,800,000 B
    unsigned short* Wt   = (unsigned short*)(ws + 25600000);   //    524,288 B
    int* counts          = (int*)(ws + 26124288);              //  3,201,024 B (NBINS)
    int* start2          = (int*)(ws + 29325312);              //  3,201,028 B (NBINS+1)
    int* blockSums       = (int*)(ws + 32526340);              //     12,504 B
    // total ~32.5 MB

    hipMemsetAsync(counts, 0, (size_t)NBINS * sizeof(int), stream);

    prep_h<<<6250, 256, 0, stream>>>(node_ids, emb, h_bf);
    prep_w<<<(NR * 128 * 128 + 255) / 256, 256, 0, stream>>>(W, Wt);
    hist_key<<<(NE + 255) / 256, 256, 0, stream>>>(dst, rel, counts);
    scanA<<<NSCB, 256, 0, stream>>>(counts, blockSums);
    scanB<<<1, 1024, 0, stream>>>(blockSums);
    scanC<<<NSCB, 256, 0, stream>>>(counts, blockSums, start2);
    scatter_rank<<<(NE + 255) / 256, 256, 0, stream>>>(src, dst, rel, norm,
                                                       counts, recs);
    rgcn_fused<<<NTILE, 256, 0, stream>>>(start2, recs,
                                          (const unsigned int*)h_bf, Wt, out);
}